// Round 12
// baseline (1200.513 us; speedup 1.0000x reference)
//
#include <hip/hip_runtime.h>
#include <stdint.h>

typedef __attribute__((ext_vector_type(4))) int i32x4;

typedef const __attribute__((address_space(1))) void gvoid_t;
typedef __attribute__((address_space(3))) void lvoid_t;

#define GLD16(g, l) __builtin_amdgcn_global_load_lds((gvoid_t*)(g), (lvoid_t*)(l), 16, 0, 0)
#define FENCE() asm volatile("" ::: "memory")
#define BARRIER() do { FENCE(); __builtin_amdgcn_s_barrier(); FENCE(); } while (0)
#define SBAR() asm volatile("s_barrier" ::: "memory")
#define LGKM0() do { asm volatile("s_waitcnt lgkmcnt(0)" ::: "memory"); __builtin_amdgcn_sched_barrier(0); } while (0)
#define GATE8() asm volatile("s_waitcnt vmcnt(8)\n\ts_barrier" ::: "memory")
#define GATE4() asm volatile("s_waitcnt vmcnt(4)\n\ts_barrier" ::: "memory")
#define GATE0() asm volatile("s_waitcnt vmcnt(0)\n\ts_barrier" ::: "memory")

// two ds_read_b128 from one address VGPR with literal offsets (compiler cannot re-place waits)
#define DSR2(d0, d1, addr, O0, O1)                                  \
    asm volatile("ds_read_b128 %0, %2 offset:" O0 "\n\t"            \
                 "ds_read_b128 %1, %2 offset:" O1                   \
                 : "=v"(d0), "=v"(d1) : "v"(addr))

__device__ inline int q1mul(float x, float r) {
    return (int)fminf(fmaxf(rintf(x * r), -128.f), 127.f);
}
__device__ inline int q1div(float x, float s) {
    return (int)fminf(fmaxf(rintf(x / s), -128.f), 127.f);
}
__device__ inline int pack4(float4 v, float r) {
    return (q1mul(v.x, r) & 255) | ((q1mul(v.y, r) & 255) << 8) |
           ((q1mul(v.z, r) & 255) << 16) | ((q1mul(v.w, r) & 255) << 24);
}

// ---------------- global absmax (4 independent chains) ----------------
__global__ void k_absmax(const float* __restrict__ x, size_t n4, unsigned int* __restrict__ out) {
    size_t S = (size_t)gridDim.x * blockDim.x;
    size_t i = (size_t)blockIdx.x * blockDim.x + threadIdx.x;
    const float4* x4 = (const float4*)x;
    float m0 = 0.f, m1 = 0.f, m2 = 0.f, m3 = 0.f;
    for (; i + 3 * S < n4; i += 4 * S) {
        float4 v0 = x4[i], v1 = x4[i + S], v2 = x4[i + 2 * S], v3 = x4[i + 3 * S];
        m0 = fmaxf(m0, fmaxf(fmaxf(fabsf(v0.x), fabsf(v0.y)), fmaxf(fabsf(v0.z), fabsf(v0.w))));
        m1 = fmaxf(m1, fmaxf(fmaxf(fabsf(v1.x), fabsf(v1.y)), fmaxf(fabsf(v1.z), fabsf(v1.w))));
        m2 = fmaxf(m2, fmaxf(fmaxf(fabsf(v2.x), fabsf(v2.y)), fmaxf(fabsf(v2.z), fabsf(v2.w))));
        m3 = fmaxf(m3, fmaxf(fmaxf(fabsf(v3.x), fabsf(v3.y)), fmaxf(fabsf(v3.z), fabsf(v3.w))));
    }
    for (; i < n4; i += S) {
        float4 v = x4[i];
        m0 = fmaxf(m0, fmaxf(fmaxf(fabsf(v.x), fabsf(v.y)), fmaxf(fabsf(v.z), fabsf(v.w))));
    }
    float m = fmaxf(fmaxf(m0, m1), fmaxf(m2, m3));
    #pragma unroll
    for (int off = 32; off > 0; off >>= 1) m = fmaxf(m, __shfl_xor(m, off, 64));
    if ((threadIdx.x & 63) == 0) atomicMax(out, __float_as_uint(m));
}

// ---------------- scale finalize ----------------
__global__ void k_scale(const float* __restrict__ clip, const unsigned int* __restrict__ maxbits,
                        float* __restrict__ s_out) {
    float m = __uint_as_float(*maxbits);
    float sig = 1.f / (1.f + expf(-clip[0]));
    float s = sig * m / 127.f;
    s_out[0] = s;
    s_out[1] = 1.f / s;
}

// ---------------- quantize fp32 -> packed int8 ----------------
__global__ void k_quant_f32_i8(const float* __restrict__ in, int4* __restrict__ out,
                               const float* __restrict__ sptr, size_t n16) {
    float r = sptr[1];
    size_t S = (size_t)gridDim.x * blockDim.x;
    size_t i = (size_t)blockIdx.x * blockDim.x + threadIdx.x;
    const float4* in4 = (const float4*)in;
    for (; i < n16; i += S) {
        float4 v0 = in4[4 * i], v1 = in4[4 * i + 1], v2 = in4[4 * i + 2], v3 = in4[4 * i + 3];
        int4 o;
        o.x = pack4(v0, r); o.y = pack4(v1, r); o.z = pack4(v2, r); o.w = pack4(v3, r);
        out[i] = o;
    }
}

// ---------------- quantize h16 (per-block scale) -> packed int8 ----------------
__global__ void k_quant_h16_i8(const short* __restrict__ h16, const float* __restrict__ sblk,
                               const float* __restrict__ sh, int4* __restrict__ qh, size_t nchunks) {
    const float rh = sh[1] * (1.f / 32766.f);
    size_t S = (size_t)gridDim.x * blockDim.x;
    size_t i = (size_t)blockIdx.x * blockDim.x + threadIdx.x;
    for (; i < nchunks; i += S) {
        int row = (int)(i / 176);
        int col = (int)(i - (size_t)row * 176) * 16;
        float f = sblk[(row >> 8) * 22 + (col >> 7)] * rh;
        const int4* p = (const int4*)(h16 + (size_t)row * 2816 + col);
        int4 lo = p[0], hi = p[1];
        int w[8] = {lo.x, lo.y, lo.z, lo.w, hi.x, hi.y, hi.z, hi.w};
        int ob[4];
        #pragma unroll
        for (int j = 0; j < 4; ++j) {
            int q0 = q1mul((float)(short)(w[2 * j] & 0xFFFF), f);
            int q1 = q1mul((float)(short)(w[2 * j] >> 16), f);
            int q2 = q1mul((float)(short)(w[2 * j + 1] & 0xFFFF), f);
            int q3 = q1mul((float)(short)(w[2 * j + 1] >> 16), f);
            ob[j] = (q0 & 255) | ((q1 & 255) << 8) | ((q2 & 255) << 16) | ((q3 & 255) << 24);
        }
        int4 o; o.x = ob[0]; o.y = ob[1]; o.z = ob[2]; o.w = ob[3];
        qh[i] = o;
    }
}

// ---------------- per-row weight quantization ----------------
__global__ void k_quant_w_i8(const float* __restrict__ W, int8_t* __restrict__ Q,
                             float* __restrict__ srow, int cols) {
    int row = blockIdx.x;
    const float* w = W + (size_t)row * cols;
    float m = 0.f;
    for (int c = threadIdx.x; c < cols; c += 256) m = fmaxf(m, fabsf(w[c]));
    #pragma unroll
    for (int off = 32; off > 0; off >>= 1) m = fmaxf(m, __shfl_xor(m, off, 64));
    __shared__ float red[4];
    if ((threadIdx.x & 63) == 0) red[threadIdx.x >> 6] = m;
    __syncthreads();
    if (threadIdx.x == 0) {
        float mm = fmaxf(fmaxf(red[0], red[1]), fmaxf(red[2], red[3]));
        red[0] = mm / 127.f;
        srow[row] = mm / 127.f;
    }
    __syncthreads();
    float s = red[0];
    for (int c = threadIdx.x; c < cols; c += 256)
        Q[(size_t)row * cols + c] = (int8_t)q1div(w[c], s);
}

// ================= GEMM1 (gate+up) — m201 instruction-level port: asm ds_read, =================
// barrier-then-lgkmcnt(0), 4-buffer ring, 3 tiles in flight, vmcnt(8) once per tile.
// Tile 256x128(g,u each), BK=64, NT=16, 512 thr (8 waves 2Mx4N).
// Buf (32 KB): A[256][64]@0 | G[128][64]@16K | U[128][64]@24K. Ring = 4 bufs = 128 KB.
__global__ __launch_bounds__(512, 2) void k_gemm1_i8(
    const int8_t* __restrict__ Aq, const int8_t* __restrict__ Bg, const int8_t* __restrict__ Bu,
    const float* __restrict__ sg, const float* __restrict__ su, const float* __restrict__ sx,
    short* __restrict__ H16, float* __restrict__ sblk, unsigned int* __restrict__ maxh,
    int nt_base)
{
    constexpr int K = 1024, N = 2816, NT = K / 64, TB = 32768;   // NT = 16
    __shared__ int8_t lds[131072];   // 4-buf ring; epilogue reuses all 128 KB

    const int wgl = (int)blockIdx.x >> 3;
    const int xcd = (int)blockIdx.x & 7;
    const int mtspan = (int)(gridDim.x >> 3) / 11;
    const int mt = xcd * mtspan + wgl / 11;
    const int nt = nt_base + wgl % 11;
    const int m0 = mt * 256, n0 = nt * 128;
    const int tid = threadIdx.x;
    const int wid = tid >> 6, lane = tid & 63;
    const int wm = wid >> 2, wn = wid & 3;
    const int lr = lane & 15, lk = lane >> 4;

    // staging: linear LDS dest, inverse-swizzled global source (rule #21)
    const int srow = tid >> 2;
    const int scol = ((tid & 3) ^ ((srow >> 1) & 3)) << 4;
    const int8_t* gA0 = Aq + (size_t)(m0 + srow) * K + scol;
    const int8_t* gA1 = gA0 + (size_t)128 * K;
    const int8_t* gG  = Bg + (size_t)(n0 + srow) * K + scol;
    const int8_t* gU  = Bu + (size_t)(n0 + srow) * K + scol;
    const int ldst = wid << 10;

    const int swz = (lk ^ ((lr >> 1) & 3)) << 4;
    const unsigned ldsBase = (unsigned)(size_t)&lds[0];           // LDS offset (low 32b of generic)
    const unsigned aoff = (unsigned)((wm * 128 + lr) * 64 + swz); // A frag base; +mi*1024
    const unsigned boff = (unsigned)(16384 + (wn * 32 + lr) * 64 + swz); // G base; U at +8192

    i32x4 accg[8][2] = {};
    i32x4 accu[8][2] = {};
    i32x4 bg[2], bu[2];

    auto stage1 = [&](int t, int q) {                // q-th wave-load of tile t into buf t&3
        int8_t* L = &lds[(t & 3) * TB];
        const size_t k0 = (size_t)t * 64;
        if (q == 0)      GLD16(gA0 + k0, L + ldst);
        else if (q == 1) GLD16(gA1 + k0, L + 8192  + ldst);
        else if (q == 2) GLD16(gG  + k0, L + 16384 + ldst);
        else             GLD16(gU  + k0, L + 24576 + ldst);
    };

    // prologue: stage tiles 0,1,2 (12 loads); vmcnt(8) -> tile 0 complete, 1 & 2 in flight
    #pragma unroll
    for (int q = 0; q < 4; ++q) stage1(0, q);
    #pragma unroll
    for (int q = 0; q < 4; ++q) stage1(1, q);
    #pragma unroll
    for (int q = 0; q < 4; ++q) stage1(2, q);
    GATE8();

#define G1_MFMA(Q, A0, A1)                                                                     \
    __builtin_amdgcn_s_setprio(1);                                                             \
    _Pragma("unroll")                                                                          \
    for (int ni = 0; ni < 2; ++ni) {                                                           \
        accg[2 * (Q)][ni]     = __builtin_amdgcn_mfma_i32_16x16x64_i8(A0, bg[ni], accg[2 * (Q)][ni], 0, 0, 0);     \
        accu[2 * (Q)][ni]     = __builtin_amdgcn_mfma_i32_16x16x64_i8(A0, bu[ni], accu[2 * (Q)][ni], 0, 0, 0);     \
        accg[2 * (Q) + 1][ni] = __builtin_amdgcn_mfma_i32_16x16x64_i8(A1, bg[ni], accg[2 * (Q) + 1][ni], 0, 0, 0); \
        accu[2 * (Q) + 1][ni] = __builtin_amdgcn_mfma_i32_16x16x64_i8(A1, bu[ni], accu[2 * (Q) + 1][ni], 0, 0, 0); \
    }                                                                                          \
    __builtin_amdgcn_s_setprio(0);

    for (int t = 0; t < NT; ++t) {
        const unsigned bufb = ldsBase + ((unsigned)(t & 3) << 15);
        const unsigned aAddr = bufb + aoff, bAddr = bufb + boff;
        const bool st3 = (t + 3 < NT);
        i32x4 a0, a1;

        // phase 0: A mi 0,1 + all B frags; stage q0 of t+3
        DSR2(a0, a1, aAddr, "0", "1024");
        DSR2(bg[0], bg[1], bAddr, "0", "1024");
        DSR2(bu[0], bu[1], bAddr, "8192", "9216");
        if (st3) stage1(t + 3, 0);
        SBAR(); LGKM0();
        G1_MFMA(0, a0, a1)
        SBAR();

        // phase 1: A mi 2,3; stage q1
        DSR2(a0, a1, aAddr, "2048", "3072");
        if (st3) stage1(t + 3, 1);
        SBAR(); LGKM0();
        G1_MFMA(1, a0, a1)
        SBAR();

        // phase 2: A mi 4,5; stage q2
        DSR2(a0, a1, aAddr, "4096", "5120");
        if (st3) stage1(t + 3, 2);
        SBAR(); LGKM0();
        G1_MFMA(2, a0, a1)
        SBAR();

        // phase 3: A mi 6,7; stage q3; tile-end gate (counted: loads waited 12 phases after issue)
        DSR2(a0, a1, aAddr, "6144", "7168");
        if (st3) stage1(t + 3, 3);
        SBAR(); LGKM0();
        G1_MFMA(3, a0, a1)
        if (t + 3 < NT)      { GATE8(); }   // outstanding: (t+2)4 + (t+3)4 after t+1 lands
        else if (t + 2 < NT) { GATE4(); }   // only (t+2)'s 4 remain
        else if (t + 1 < NT) { GATE0(); }
        else                 { SBAR(); }
    }
#undef G1_MFMA

    // ---- epilogue (R8-verified): single SwiGLU pass -> f32 LDS tile -> coalesced int16 stores ----
    const float s_x = sx[0];
    float lmax = 0.f;
    #pragma unroll
    for (int ni = 0; ni < 2; ++ni) {
        const int nl = wn * 32 + ni * 16 + lr;
        const float fg = s_x * sg[n0 + nl];
        const float fu = s_x * su[n0 + nl];
        #pragma unroll
        for (int mi = 0; mi < 8; ++mi) {
            const int rowb = wm * 128 + mi * 16 + lk * 4;
            #pragma unroll
            for (int r = 0; r < 4; ++r) {
                float g = (float)accg[mi][ni][r] * fg;
                float u = (float)accu[mi][ni][r] * fu;
                float h = g * u / (1.f + expf(-g));
                *(float*)(lds + ((rowb + r) << 9) + (nl << 2)) = h;
                lmax = fmaxf(lmax, fabsf(h));
            }
        }
    }
    #pragma unroll
    for (int off = 32; off > 0; off >>= 1) lmax = fmaxf(lmax, __shfl_xor(lmax, off, 64));
    unsigned int* slot = (unsigned int*)&sblk[mt * 22 + nt];
    if (lane == 0) atomicMax(slot, __float_as_uint(lmax));
    BARRIER();
    const float bmax = __uint_as_float(*slot);
    if (tid == 0) atomicMax(maxh, __float_as_uint(bmax));
    const float qs = 32766.f / fmaxf(bmax, 1e-20f);
    uint* H16u = (uint*)H16;
    #pragma unroll
    for (int k = 0; k < 32; ++k) {
        const int fidx = 2 * (tid + k * 512);
        const int row = fidx >> 7, c2 = fidx & 127;
        const float2 hv = *(const float2*)(lds + (fidx << 2));
        const int s0 = (int)rintf(hv.x * qs), s1 = (int)rintf(hv.y * qs);
        H16u[((size_t)(m0 + row) * N + n0 + c2) >> 1] = (s0 & 0xFFFF) | (s1 << 16);
    }
}

// ================= GEMM2 — same instruction-level schedule, 256x256, NT=44 =================
// Buf (32 KB): A[256][64]@0 | B[256][64]@16K. Ring = 4 bufs = 128 KB.
__global__ __launch_bounds__(512, 2) void k_gemm2_i8(
    const int8_t* __restrict__ Aq, const int8_t* __restrict__ Bw,
    const float* __restrict__ sw, const float* __restrict__ sh,
    float* __restrict__ Out)
{
    constexpr int K = 2816, N = 1024, NT = K / 64, TB = 32768;   // NT = 44 (44 % 4 == 0)
    __shared__ int8_t lds[131072];

    const int chunk = gridDim.x >> 3;                // grid = 1024 = 8*128
    const int wg = ((int)blockIdx.x & 7) * chunk + ((int)blockIdx.x >> 3);
    const int mt = wg >> 2, nt = wg & 3;
    const int m0 = mt * 256, n0 = nt * 256;
    const int tid = threadIdx.x;
    const int wid = tid >> 6, lane = tid & 63;
    const int wm = wid >> 2, wn = wid & 3;
    const int lr = lane & 15, lk = lane >> 4;

    const int srow = tid >> 2;
    const int scol = ((tid & 3) ^ ((srow >> 1) & 3)) << 4;
    const int8_t* gA0 = Aq + (size_t)(m0 + srow) * K + scol;
    const int8_t* gA1 = gA0 + (size_t)128 * K;
    const int8_t* gB0 = Bw + (size_t)(n0 + srow) * K + scol;
    const int8_t* gB1 = gB0 + (size_t)128 * K;
    const int ldst = wid << 10;

    const int swz = (lk ^ ((lr >> 1) & 3)) << 4;
    const unsigned ldsBase = (unsigned)(size_t)&lds[0];
    const unsigned aoff = (unsigned)((wm * 128 + lr) * 64 + swz);
    const unsigned boff = (unsigned)(16384 + (wn * 64 + lr) * 64 + swz);

    i32x4 acc[8][4] = {};
    i32x4 b[4];

    auto stage1 = [&](int t, int q) {
        int8_t* L = &lds[(t & 3) * TB];
        const size_t k0 = (size_t)t * 64;
        if (q == 0)      GLD16(gA0 + k0, L + ldst);
        else if (q == 1) GLD16(gA1 + k0, L + 8192  + ldst);
        else if (q == 2) GLD16(gB0 + k0, L + 16384 + ldst);
        else             GLD16(gB1 + k0, L + 24576 + ldst);
    };

    #pragma unroll
    for (int q = 0; q < 4; ++q) stage1(0, q);
    #pragma unroll
    for (int q = 0; q < 4; ++q) stage1(1, q);
    #pragma unroll
    for (int q = 0; q < 4; ++q) stage1(2, q);
    GATE8();

#define G2_MFMA(Q, A0, A1)                                                                     \
    __builtin_amdgcn_s_setprio(1);                                                             \
    _Pragma("unroll")                                                                          \
    for (int ni = 0; ni < 4; ++ni) {                                                           \
        acc[2 * (Q)][ni]     = __builtin_amdgcn_mfma_i32_16x16x64_i8(A0, b[ni], acc[2 * (Q)][ni], 0, 0, 0);     \
        acc[2 * (Q) + 1][ni] = __builtin_amdgcn_mfma_i32_16x16x64_i8(A1, b[ni], acc[2 * (Q) + 1][ni], 0, 0, 0); \
    }                                                                                          \
    __builtin_amdgcn_s_setprio(0);

    for (int t = 0; t < NT; ++t) {
        const unsigned bufb = ldsBase + ((unsigned)(t & 3) << 15);
        const unsigned aAddr = bufb + aoff, bAddr = bufb + boff;
        const bool st3 = (t + 3 < NT);
        i32x4 a0, a1;

        DSR2(a0, a1, aAddr, "0", "1024");
        DSR2(b[0], b[1], bAddr, "0", "1024");
        DSR2(b[2], b[3], bAddr, "2048", "3072");
        if (st3) stage1(t + 3, 0);
        SBAR(); LGKM0();
        G2_MFMA(0, a0, a1)
        SBAR();

        DSR2(a0, a1, aAddr, "2048", "3072");
        if (st3) stage1(t + 3, 1);
        SBAR(); LGKM0();
        G2_MFMA(1, a0, a1)
        SBAR();

        DSR2(a0, a1, aAddr, "4096", "5120");
        if (st3) stage1(t + 3, 2);
        SBAR(); LGKM0();
        G2_MFMA(2, a0, a1)
        SBAR();

        DSR2(a0, a1, aAddr, "6144", "7168");
        if (st3) stage1(t + 3, 3);
        SBAR(); LGKM0();
        G2_MFMA(3, a0, a1)
        if (t + 3 < NT)      { GATE8(); }
        else if (t + 2 < NT) { GATE4(); }
        else if (t + 1 < NT) { GATE0(); }
        else                 { SBAR(); }
    }
#undef G2_MFMA

    const float s_h = sh[0];
    #pragma unroll
    for (int ni = 0; ni < 4; ++ni) {
        const int n = n0 + wn * 64 + ni * 16 + lr;
        const float f = s_h * sw[n];
        #pragma unroll
        for (int mi = 0; mi < 8; ++mi) {
            const int mb = m0 + wm * 128 + mi * 16 + lk * 4;
            #pragma unroll
            for (int r = 0; r < 4; ++r)
                Out[(size_t)(mb + r) * N + n] = (float)acc[mi][ni][r] * f;
        }
    }
}

extern "C" void kernel_launch(void* const* d_in, const int* in_sizes, int n_in,
                              void* d_out, int out_size, void* d_ws, size_t ws_size,
                              hipStream_t stream) {
    const float* x       = (const float*)d_in[0];
    const float* clip_x  = (const float*)d_in[1];
    const float* clip_dn = (const float*)d_in[2];
    const float* w_gate  = (const float*)d_in[3];
    const float* w_up    = (const float*)d_in[4];
    const float* w_down  = (const float*)d_in[5];
    float* out = (float*)d_out;

    const int Hd = 1024, Id = 2816;
    const int M = in_sizes[0] / Hd;                  // 65536
    const size_t nx = (size_t)M * Hd;
    const size_t nh = (size_t)M * Id;

    char* ws = (char*)d_ws;
    size_t off = 0;
    auto alloc = [&](size_t bytes) -> char* {
        char* p = ws + off;
        off = (off + bytes + 255) & ~(size_t)255;
        return p;
    };
    unsigned int* max_slots = (unsigned int*)alloc(8);   // [0]=max|x|, [1]=max|h|
    float* sxp = (float*)alloc(8);
    float* shp = (float*)alloc(8);
    int8_t* qx  = (int8_t*)alloc(nx);
    int8_t* qwg = (int8_t*)alloc((size_t)Id * Hd);
    int8_t* qwu = (int8_t*)alloc((size_t)Id * Hd);
    int8_t* qwd = (int8_t*)alloc((size_t)Hd * Id);
    float* swg = (float*)alloc((size_t)Id * 4);
    float* swu = (float*)alloc((size_t)Id * 4);
    float* swd = (float*)alloc((size_t)Hd * 4);
    int8_t* qh = (int8_t*)alloc(nh);
    short* h16 = (short*)alloc(nh * 2);
    const size_t sblk_bytes = (size_t)(M / 256) * 22 * 4;
    float* sblk = (float*)alloc(sblk_bytes);

    hipMemsetAsync(max_slots, 0, 8, stream);
    hipMemsetAsync(sblk, 0, sblk_bytes, stream);

    k_absmax<<<4096, 256, 0, stream>>>(x, nx / 4, &max_slots[0]);
    k_scale<<<1, 1, 0, stream>>>(clip_x, &max_slots[0], sxp);
    k_quant_f32_i8<<<2048, 256, 0, stream>>>(x, (int4*)qx, sxp, nx / 16);
    k_quant_w_i8<<<Id, 256, 0, stream>>>(w_gate, qwg, swg, Hd);
    k_quant_w_i8<<<Id, 256, 0, stream>>>(w_up, qwu, swu, Hd);
    k_quant_w_i8<<<Hd, 256, 0, stream>>>(w_down, qwd, swd, Id);

    const int g1grid = (M / 256) * 11;               // per nt-half
    k_gemm1_i8<<<g1grid, 512, 0, stream>>>(qx, qwg, qwu, swg, swu, sxp, h16, sblk, &max_slots[1], 0);
    k_gemm1_i8<<<g1grid, 512, 0, stream>>>(qx, qwg, qwu, swg, swu, sxp, h16, sblk, &max_slots[1], 11);
    k_scale<<<1, 1, 0, stream>>>(clip_dn, &max_slots[1], shp);
    k_quant_h16_i8<<<4096, 256, 0, stream>>>(h16, sblk, shp, (int4*)qh, nh / 16);

    k_gemm2_i8<<<(M / 256) * (Hd / 256), 512, 0, stream>>>(qh, qwd, swd, shp, out);
}

// Round 13
// 1137.204 us; speedup vs baseline: 1.0557x; 1.0557x over previous
//
#include <hip/hip_runtime.h>
#include <stdint.h>

typedef __attribute__((ext_vector_type(4))) int i32x4;

typedef const __attribute__((address_space(1))) void gvoid_t;
typedef __attribute__((address_space(3))) void lvoid_t;

#define GLD16(g, l) __builtin_amdgcn_global_load_lds((gvoid_t*)(g), (lvoid_t*)(l), 16, 0, 0)
#define FENCE() asm volatile("" ::: "memory")
#define BARRIER() do { FENCE(); __builtin_amdgcn_s_barrier(); FENCE(); } while (0)
#define SCHEDB() __builtin_amdgcn_sched_barrier(0)
#define GATE(n) asm volatile("s_waitcnt vmcnt(" #n ")\n\ts_barrier" ::: "memory")

__device__ inline int q1mul(float x, float r) {
    return (int)fminf(fmaxf(rintf(x * r), -128.f), 127.f);
}
__device__ inline int q1div(float x, float s) {
    return (int)fminf(fmaxf(rintf(x / s), -128.f), 127.f);
}
__device__ inline int pack4(float4 v, float r) {
    return (q1mul(v.x, r) & 255) | ((q1mul(v.y, r) & 255) << 8) |
           ((q1mul(v.z, r) & 255) << 16) | ((q1mul(v.w, r) & 255) << 24);
}

// ---------------- global absmax (4 independent chains) ----------------
__global__ void k_absmax(const float* __restrict__ x, size_t n4, unsigned int* __restrict__ out) {
    size_t S = (size_t)gridDim.x * blockDim.x;
    size_t i = (size_t)blockIdx.x * blockDim.x + threadIdx.x;
    const float4* x4 = (const float4*)x;
    float m0 = 0.f, m1 = 0.f, m2 = 0.f, m3 = 0.f;
    for (; i + 3 * S < n4; i += 4 * S) {
        float4 v0 = x4[i], v1 = x4[i + S], v2 = x4[i + 2 * S], v3 = x4[i + 3 * S];
        m0 = fmaxf(m0, fmaxf(fmaxf(fabsf(v0.x), fabsf(v0.y)), fmaxf(fabsf(v0.z), fabsf(v0.w))));
        m1 = fmaxf(m1, fmaxf(fmaxf(fabsf(v1.x), fabsf(v1.y)), fmaxf(fabsf(v1.z), fabsf(v1.w))));
        m2 = fmaxf(m2, fmaxf(fmaxf(fabsf(v2.x), fabsf(v2.y)), fmaxf(fabsf(v2.z), fabsf(v2.w))));
        m3 = fmaxf(m3, fmaxf(fmaxf(fabsf(v3.x), fabsf(v3.y)), fmaxf(fabsf(v3.z), fabsf(v3.w))));
    }
    for (; i < n4; i += S) {
        float4 v = x4[i];
        m0 = fmaxf(m0, fmaxf(fmaxf(fabsf(v.x), fabsf(v.y)), fmaxf(fabsf(v.z), fabsf(v.w))));
    }
    float m = fmaxf(fmaxf(m0, m1), fmaxf(m2, m3));
    #pragma unroll
    for (int off = 32; off > 0; off >>= 1) m = fmaxf(m, __shfl_xor(m, off, 64));
    if ((threadIdx.x & 63) == 0) atomicMax(out, __float_as_uint(m));
}

// ---------------- scale finalize ----------------
__global__ void k_scale(const float* __restrict__ clip, const unsigned int* __restrict__ maxbits,
                        float* __restrict__ s_out) {
    float m = __uint_as_float(*maxbits);
    float sig = 1.f / (1.f + expf(-clip[0]));
    float s = sig * m / 127.f;
    s_out[0] = s;
    s_out[1] = 1.f / s;
}

// ---------------- quantize fp32 -> packed int8 ----------------
__global__ void k_quant_f32_i8(const float* __restrict__ in, int4* __restrict__ out,
                               const float* __restrict__ sptr, size_t n16) {
    float r = sptr[1];
    size_t S = (size_t)gridDim.x * blockDim.x;
    size_t i = (size_t)blockIdx.x * blockDim.x + threadIdx.x;
    const float4* in4 = (const float4*)in;
    for (; i < n16; i += S) {
        float4 v0 = in4[4 * i], v1 = in4[4 * i + 1], v2 = in4[4 * i + 2], v3 = in4[4 * i + 3];
        int4 o;
        o.x = pack4(v0, r); o.y = pack4(v1, r); o.z = pack4(v2, r); o.w = pack4(v3, r);
        out[i] = o;
    }
}

// ---------------- quantize h16 (per-block scale) -> packed int8 ----------------
__global__ void k_quant_h16_i8(const short* __restrict__ h16, const float* __restrict__ sblk,
                               const float* __restrict__ sh, int4* __restrict__ qh, size_t nchunks) {
    const float rh = sh[1] * (1.f / 32766.f);
    size_t S = (size_t)gridDim.x * blockDim.x;
    size_t i = (size_t)blockIdx.x * blockDim.x + threadIdx.x;
    for (; i < nchunks; i += S) {
        int row = (int)(i / 176);
        int col = (int)(i - (size_t)row * 176) * 16;
        float f = sblk[(row >> 8) * 22 + (col >> 7)] * rh;
        const int4* p = (const int4*)(h16 + (size_t)row * 2816 + col);
        int4 lo = p[0], hi = p[1];
        int w[8] = {lo.x, lo.y, lo.z, lo.w, hi.x, hi.y, hi.z, hi.w};
        int ob[4];
        #pragma unroll
        for (int j = 0; j < 4; ++j) {
            int q0 = q1mul((float)(short)(w[2 * j] & 0xFFFF), f);
            int q1 = q1mul((float)(short)(w[2 * j] >> 16), f);
            int q2 = q1mul((float)(short)(w[2 * j + 1] & 0xFFFF), f);
            int q3 = q1mul((float)(short)(w[2 * j + 1] >> 16), f);
            ob[j] = (q0 & 255) | ((q1 & 255) << 8) | ((q2 & 255) << 16) | ((q3 & 255) << 24);
        }
        int4 o; o.x = ob[0]; o.y = ob[1]; o.z = ob[2]; o.w = ob[3];
        qh[i] = o;
    }
}

// ---------------- per-row weight quantization ----------------
__global__ void k_quant_w_i8(const float* __restrict__ W, int8_t* __restrict__ Q,
                             float* __restrict__ srow, int cols) {
    int row = blockIdx.x;
    const float* w = W + (size_t)row * cols;
    float m = 0.f;
    for (int c = threadIdx.x; c < cols; c += 256) m = fmaxf(m, fabsf(w[c]));
    #pragma unroll
    for (int off = 32; off > 0; off >>= 1) m = fmaxf(m, __shfl_xor(m, off, 64));
    __shared__ float red[4];
    if ((threadIdx.x & 63) == 0) red[threadIdx.x >> 6] = m;
    __syncthreads();
    if (threadIdx.x == 0) {
        float mm = fmaxf(fmaxf(red[0], red[1]), fmaxf(red[2], red[3]));
        red[0] = mm / 127.f;
        srow[row] = mm / 127.f;
    }
    __syncthreads();
    float s = red[0];
    for (int c = threadIdx.x; c < cols; c += 256)
        Q[(size_t)row * cols + c] = (int8_t)q1div(w[c], s);
}

#define MFMA_G1(AF, BG, BU, OFF)                                                              \
    _Pragma("unroll")                                                                         \
    for (int mi = 0; mi < 4; ++mi) {                                                          \
        _Pragma("unroll")                                                                     \
        for (int ni = 0; ni < 2; ++ni) {                                                      \
            accg[(OFF) + mi][ni] = __builtin_amdgcn_mfma_i32_16x16x64_i8(AF[mi], BG[ni], accg[(OFF) + mi][ni], 0, 0, 0); \
            accu[(OFF) + mi][ni] = __builtin_amdgcn_mfma_i32_16x16x64_i8(AF[mi], BU[ni], accu[(OFF) + mi][ni], 0, 0, 0); \
        }                                                                                     \
    }

// ================= GEMM1 (gate+up) — register read-ahead pipeline, 2 gates/K-tile (R9-best) =================
// Tile 256x128(g,u each), BK=128 (two 64B k-slabs). LDS/buf 64K: A0@0 A1@16K G0@32K U0@40K G1@48K U1@56K.
// Each phase's ds_reads load the NEXT phase's fragments -> LDS pipe runs under the MFMA window.
__global__ __launch_bounds__(512, 2) void k_gemm1_i8(
    const int8_t* __restrict__ Aq, const int8_t* __restrict__ Bg, const int8_t* __restrict__ Bu,
    const float* __restrict__ sg, const float* __restrict__ su, const float* __restrict__ sx,
    short* __restrict__ H16, float* __restrict__ sblk, unsigned int* __restrict__ maxh,
    int nt_base)
{
    constexpr int K = 1024, N = 2816, NT = K / 128, BUF = 65536;
    __shared__ int8_t lds[2 * BUF];

    const int wgl = (int)blockIdx.x >> 3;
    const int xcd = (int)blockIdx.x & 7;
    const int mtspan = (int)(gridDim.x >> 3) / 11;
    const int mt = xcd * mtspan + wgl / 11;
    const int nt = nt_base + wgl % 11;
    const int m0 = mt * 256, n0 = nt * 128;
    const int tid = threadIdx.x;
    const int wid = tid >> 6, lane = tid & 63;
    const int wm = wid >> 2, wn = wid & 3;
    const int lr = lane & 15, lk = lane >> 4;

    const int srow = tid >> 2;
    const int scol = ((tid & 3) ^ ((srow >> 1) & 3)) << 4;
    const int8_t* gA0 = Aq + (size_t)(m0 + srow) * K + scol;
    const int8_t* gA1 = gA0 + (size_t)128 * K;
    const int8_t* gG  = Bg + (size_t)(n0 + srow) * K + scol;
    const int8_t* gU  = Bu + (size_t)(n0 + srow) * K + scol;
    const int ldst = wid << 10;

    const int swz = (lk ^ ((lr >> 1) & 3)) << 4;
    const int aoff = (wm * 128 + lr) * 64 + swz;          // + mi*1024; mh1 +4096; A1 +16384
    const int boffG = 32768 + (wn * 32 + lr) * 64 + swz;  // + ni*1024; G1/U1 +16384
    const int boffU = 40960 + (wn * 32 + lr) * 64 + swz;

    i32x4 accg[8][2] = {};
    i32x4 accu[8][2] = {};
    i32x4 aA[4], aB[4], bgA[2], buA[2], bgB[2], buB[2];

    // prologue: tile0 GLD order = A0,G0U0 | A1,G1U1
    {
        int8_t* Lw = &lds[0];
        GLD16(gA0,      Lw + ldst);         GLD16(gA1,      Lw + 8192  + ldst);
        GLD16(gG,       Lw + 32768 + ldst); GLD16(gU,       Lw + 40960 + ldst);
        GLD16(gA0 + 64, Lw + 16384 + ldst); GLD16(gA1 + 64, Lw + 24576 + ldst);
        GLD16(gG  + 64, Lw + 49152 + ldst); GLD16(gU  + 64, Lw + 57344 + ldst);
    }
    GATE(4);                                              // A0,G0U0(0) landed for everyone
    {
        const int8_t* Lr = &lds[0];
        #pragma unroll
        for (int mi = 0; mi < 4; ++mi) aA[mi] = *(const i32x4*)(Lr + aoff + mi * 1024);
        #pragma unroll
        for (int ni = 0; ni < 2; ++ni) {
            bgA[ni] = *(const i32x4*)(Lr + boffG + ni * 1024);
            buA[ni] = *(const i32x4*)(Lr + boffU + ni * 1024);
        }
    }

    for (int t = 0; t < NT; ++t) {
        const bool st = (t + 1 < NT);
        const int8_t* Lr = &lds[(t & 1) * BUF];
        int8_t* Lw = &lds[((t + 1) & 1) * BUF];
        const size_t kk = (size_t)(t + 1) * 128;

        // pA: read A0mh1->aB; stage A0(t+1); MFMA(A0mh0 x G0U0 -> quad0)
        #pragma unroll
        for (int mi = 0; mi < 4; ++mi) aB[mi] = *(const i32x4*)(Lr + aoff + 4096 + mi * 1024);
        if (st) { GLD16(gA0 + kk, Lw + ldst); GLD16(gA1 + kk, Lw + 8192 + ldst); }
        SCHEDB();
        __builtin_amdgcn_s_setprio(1);
        MFMA_G1(aA, bgA, buA, 0);
        __builtin_amdgcn_s_setprio(0);
        // gate2: pB reads A1,G1U1(t) staged in pC(t-1). outstanding = pC(t-1)4 + pA2 -> vmcnt(2).
        if (st) { GATE(2); } else { GATE(0); }

        // pB: read A1mh0->aA, G1U1->bgB/buB; stage G0U0(t+1); MFMA(A0mh1 x G0U0 -> quad4)
        #pragma unroll
        for (int mi = 0; mi < 4; ++mi) aA[mi] = *(const i32x4*)(Lr + 16384 + aoff + mi * 1024);
        #pragma unroll
        for (int ni = 0; ni < 2; ++ni) {
            bgB[ni] = *(const i32x4*)(Lr + 16384 + boffG + ni * 1024);
            buB[ni] = *(const i32x4*)(Lr + 16384 + boffU + ni * 1024);
        }
        if (st) { GLD16(gG + kk, Lw + 32768 + ldst); GLD16(gU + kk, Lw + 40960 + ldst); }
        SCHEDB();
        __builtin_amdgcn_s_setprio(1);
        MFMA_G1(aB, bgA, buA, 4);
        __builtin_amdgcn_s_setprio(0);

        // pC: read A1mh1->aB; stage A1(t+1)+G1U1(t+1); MFMA(A1mh0 x G1U1 -> quad0)
        #pragma unroll
        for (int mi = 0; mi < 4; ++mi) aB[mi] = *(const i32x4*)(Lr + 16384 + aoff + 4096 + mi * 1024);
        if (st) { GLD16(gA0 + kk + 64, Lw + 16384 + ldst); GLD16(gA1 + kk + 64, Lw + 24576 + ldst);
                  GLD16(gG + kk + 64, Lw + 49152 + ldst);  GLD16(gU + kk + 64, Lw + 57344 + ldst); }
        SCHEDB();
        __builtin_amdgcn_s_setprio(1);
        MFMA_G1(aA, bgB, buB, 0);
        __builtin_amdgcn_s_setprio(0);
        // gate1: pD reads A0,G0U0(t+1) staged in pA/pB(t). outstanding = pA2+pB2+pC4 -> vmcnt(4).
        if (st) { GATE(4); } else { GATE(0); }

        // pD: read A0mh0(t+1)->aA, G0U0(t+1)->bgA/buA (from Lw); MFMA(A1mh1 x G1U1 -> quad4)
        if (st) {
            #pragma unroll
            for (int mi = 0; mi < 4; ++mi) aA[mi] = *(const i32x4*)(Lw + aoff + mi * 1024);
            #pragma unroll
            for (int ni = 0; ni < 2; ++ni) {
                bgA[ni] = *(const i32x4*)(Lw + boffG + ni * 1024);
                buA[ni] = *(const i32x4*)(Lw + boffU + ni * 1024);
            }
        }
        SCHEDB();
        __builtin_amdgcn_s_setprio(1);
        MFMA_G1(aB, bgB, buB, 4);
        __builtin_amdgcn_s_setprio(0);
    }
    BARRIER();                                            // all LDS frag reads drained before h overwrites LDS

    // ---- epilogue (R8): single SwiGLU pass -> LDS -> coalesced int16 stores ----
    const float s_x = sx[0];
    float lmax = 0.f;
    #pragma unroll
    for (int ni = 0; ni < 2; ++ni) {
        const int nl = wn * 32 + ni * 16 + lr;
        const float fg = s_x * sg[n0 + nl];
        const float fu = s_x * su[n0 + nl];
        #pragma unroll
        for (int mi = 0; mi < 8; ++mi) {
            const int rowb = wm * 128 + mi * 16 + lk * 4;
            #pragma unroll
            for (int r = 0; r < 4; ++r) {
                float g = (float)accg[mi][ni][r] * fg;
                float u = (float)accu[mi][ni][r] * fu;
                float h = g * u / (1.f + expf(-g));
                *(float*)(lds + ((rowb + r) << 9) + (nl << 2)) = h;
                lmax = fmaxf(lmax, fabsf(h));
            }
        }
    }
    #pragma unroll
    for (int off = 32; off > 0; off >>= 1) lmax = fmaxf(lmax, __shfl_xor(lmax, off, 64));
    unsigned int* slot = (unsigned int*)&sblk[mt * 22 + nt];
    if (lane == 0) atomicMax(slot, __float_as_uint(lmax));
    BARRIER();
    const float bmax = __uint_as_float(*slot);
    if (tid == 0) atomicMax(maxh, __float_as_uint(bmax));
    const float qs = 32766.f / fmaxf(bmax, 1e-20f);
    uint* H16u = (uint*)H16;
    #pragma unroll
    for (int k = 0; k < 32; ++k) {
        const int fidx = 2 * (tid + k * 512);
        const int row = fidx >> 7, col = fidx & 127;
        const float2 hv = *(const float2*)(lds + (fidx << 2));
        const int s0 = (int)rintf(hv.x * qs), s1 = (int)rintf(hv.y * qs);
        H16u[((size_t)(m0 + row) * N + n0 + col) >> 1] = (s0 & 0xFFFF) | (s1 << 16);
    }
}

#define MFMA_G2(AF, BF, OFF)                                                                  \
    _Pragma("unroll")                                                                         \
    for (int mi = 0; mi < 4; ++mi) {                                                          \
        _Pragma("unroll")                                                                     \
        for (int ni = 0; ni < 4; ++ni)                                                        \
            acc[(OFF) + mi][ni] = __builtin_amdgcn_mfma_i32_16x16x64_i8(AF[mi], BF[ni], acc[(OFF) + mi][ni], 0, 0, 0); \
    }

// ================= GEMM2 — same read-ahead pipeline, 256x256 =================
// LDS/buf 64K: A0@0 A1@16K B0@32K B1@48K.
__global__ __launch_bounds__(512, 2) void k_gemm2_i8(
    const int8_t* __restrict__ Aq, const int8_t* __restrict__ Bw,
    const float* __restrict__ sw, const float* __restrict__ sh,
    float* __restrict__ Out)
{
    constexpr int K = 2816, N = 1024, NT = K / 128, BUF = 65536;   // NT = 22
    __shared__ int8_t lds[2 * BUF];

    const int chunk = gridDim.x >> 3;                // grid = 1024 = 8*128
    const int wg = ((int)blockIdx.x & 7) * chunk + ((int)blockIdx.x >> 3);
    const int mt = wg >> 2, nt = wg & 3;
    const int m0 = mt * 256, n0 = nt * 256;
    const int tid = threadIdx.x;
    const int wid = tid >> 6, lane = tid & 63;
    const int wm = wid >> 2, wn = wid & 3;
    const int lr = lane & 15, lk = lane >> 4;

    const int srow = tid >> 2;
    const int scol = ((tid & 3) ^ ((srow >> 1) & 3)) << 4;
    const int8_t* gA0 = Aq + (size_t)(m0 + srow) * K + scol;
    const int8_t* gA1 = gA0 + (size_t)128 * K;
    const int8_t* gB0 = Bw + (size_t)(n0 + srow) * K + scol;
    const int8_t* gB1 = gB0 + (size_t)128 * K;
    const int ldst = wid << 10;

    const int swz = (lk ^ ((lr >> 1) & 3)) << 4;
    const int aoff = (wm * 128 + lr) * 64 + swz;
    const int boff = 32768 + (wn * 64 + lr) * 64 + swz;   // + ni*1024; B1 +16384

    i32x4 acc[8][4] = {};
    i32x4 aA[4], aB[4], bA[4], bB[4];

    {
        int8_t* Lw = &lds[0];
        GLD16(gA0,      Lw + ldst);         GLD16(gA1,      Lw + 8192  + ldst);
        GLD16(gB0,      Lw + 32768 + ldst); GLD16(gB1,      Lw + 40960 + ldst);
        GLD16(gA0 + 64, Lw + 16384 + ldst); GLD16(gA1 + 64, Lw + 24576 + ldst);
        GLD16(gB0 + 64, Lw + 49152 + ldst); GLD16(gB1 + 64, Lw + 57344 + ldst);
    }
    GATE(4);
    {
        const int8_t* Lr = &lds[0];
        #pragma unroll
        for (int mi = 0; mi < 4; ++mi) aA[mi] = *(const i32x4*)(Lr + aoff + mi * 1024);
        #pragma unroll
        for (int ni = 0; ni < 4; ++ni) bA[ni] = *(const i32x4*)(Lr + boff + ni * 1024);
    }

    for (int t = 0; t < NT; ++t) {
        const bool st = (t + 1 < NT);
        const int8_t* Lr = &lds[(t & 1) * BUF];
        int8_t* Lw = &lds[((t + 1) & 1) * BUF];
        const size_t kk = (size_t)(t + 1) * 128;

        // pA
        #pragma unroll
        for (int mi = 0; mi < 4; ++mi) aB[mi] = *(const i32x4*)(Lr + aoff + 4096 + mi * 1024);
        if (st) { GLD16(gA0 + kk, Lw + ldst); GLD16(gA1 + kk, Lw + 8192 + ldst); }
        SCHEDB();
        __builtin_amdgcn_s_setprio(1);
        MFMA_G2(aA, bA, 0);
        __builtin_amdgcn_s_setprio(0);
        if (st) { GATE(2); } else { GATE(0); }

        // pB
        #pragma unroll
        for (int mi = 0; mi < 4; ++mi) aA[mi] = *(const i32x4*)(Lr + 16384 + aoff + mi * 1024);
        #pragma unroll
        for (int ni = 0; ni < 4; ++ni) bB[ni] = *(const i32x4*)(Lr + 16384 + boff + ni * 1024);
        if (st) { GLD16(gB0 + kk, Lw + 32768 + ldst); GLD16(gB1 + kk, Lw + 40960 + ldst); }
        SCHEDB();
        __builtin_amdgcn_s_setprio(1);
        MFMA_G2(aB, bA, 4);
        __builtin_amdgcn_s_setprio(0);

        // pC
        #pragma unroll
        for (int mi = 0; mi < 4; ++mi) aB[mi] = *(const i32x4*)(Lr + 16384 + aoff + 4096 + mi * 1024);
        if (st) { GLD16(gA0 + kk + 64, Lw + 16384 + ldst); GLD16(gA1 + kk + 64, Lw + 24576 + ldst);
                  GLD16(gB0 + kk + 64, Lw + 49152 + ldst); GLD16(gB1 + kk + 64, Lw + 57344 + ldst); }
        SCHEDB();
        __builtin_amdgcn_s_setprio(1);
        MFMA_G2(aA, bB, 0);
        __builtin_amdgcn_s_setprio(0);
        if (st) { GATE(4); } else { GATE(0); }

        // pD
        if (st) {
            #pragma unroll
            for (int mi = 0; mi < 4; ++mi) aA[mi] = *(const i32x4*)(Lw + aoff + mi * 1024);
            #pragma unroll
            for (int ni = 0; ni < 4; ++ni) bA[ni] = *(const i32x4*)(Lw + boff + ni * 1024);
        }
        SCHEDB();
        __builtin_amdgcn_s_setprio(1);
        MFMA_G2(aB, bB, 4);
        __builtin_amdgcn_s_setprio(0);
    }

    const float s_h = sh[0];
    #pragma unroll
    for (int ni = 0; ni < 4; ++ni) {
        const int n = n0 + wn * 64 + ni * 16 + lr;
        const float f = s_h * sw[n];
        #pragma unroll
        for (int mi = 0; mi < 8; ++mi) {
            const int mb = m0 + wm * 128 + mi * 16 + lk * 4;
            #pragma unroll
            for (int r = 0; r < 4; ++r)
                Out[(size_t)(mb + r) * N + n] = (float)acc[mi][ni][r] * f;
        }
    }
}

extern "C" void kernel_launch(void* const* d_in, const int* in_sizes, int n_in,
                              void* d_out, int out_size, void* d_ws, size_t ws_size,
                              hipStream_t stream) {
    const float* x       = (const float*)d_in[0];
    const float* clip_x  = (const float*)d_in[1];
    const float* clip_dn = (const float*)d_in[2];
    const float* w_gate  = (const float*)d_in[3];
    const float* w_up    = (const float*)d_in[4];
    const float* w_down  = (const float*)d_in[5];
    float* out = (float*)d_out;

    const int Hd = 1024, Id = 2816;
    const int M = in_sizes[0] / Hd;                  // 65536
    const size_t nx = (size_t)M * Hd;
    const size_t nh = (size_t)M * Id;

    char* ws = (char*)d_ws;
    size_t off = 0;
    auto alloc = [&](size_t bytes) -> char* {
        char* p = ws + off;
        off = (off + bytes + 255) & ~(size_t)255;
        return p;
    };
    unsigned int* max_slots = (unsigned int*)alloc(8);   // [0]=max|x|, [1]=max|h|
    float* sxp = (float*)alloc(8);
    float* shp = (float*)alloc(8);
    int8_t* qx  = (int8_t*)alloc(nx);
    int8_t* qwg = (int8_t*)alloc((size_t)Id * Hd);
    int8_t* qwu = (int8_t*)alloc((size_t)Id * Hd);
    int8_t* qwd = (int8_t*)alloc((size_t)Hd * Id);
    float* swg = (float*)alloc((size_t)Id * 4);
    float* swu = (float*)alloc((size_t)Id * 4);
    float* swd = (float*)alloc((size_t)Hd * 4);
    int8_t* qh = (int8_t*)alloc(nh);
    short* h16 = (short*)alloc(nh * 2);
    const size_t sblk_bytes = (size_t)(M / 256) * 22 * 4;
    float* sblk = (float*)alloc(sblk_bytes);

    hipMemsetAsync(max_slots, 0, 8, stream);
    hipMemsetAsync(sblk, 0, sblk_bytes, stream);

    k_absmax<<<4096, 256, 0, stream>>>(x, nx / 4, &max_slots[0]);
    k_scale<<<1, 1, 0, stream>>>(clip_x, &max_slots[0], sxp);
    k_quant_f32_i8<<<2048, 256, 0, stream>>>(x, (int4*)qx, sxp, nx / 16);
    k_quant_w_i8<<<Id, 256, 0, stream>>>(w_gate, qwg, swg, Hd);
    k_quant_w_i8<<<Id, 256, 0, stream>>>(w_up, qwu, swu, Hd);
    k_quant_w_i8<<<Hd, 256, 0, stream>>>(w_down, qwd, swd, Id);

    const int g1grid = (M / 256) * 11;               // per nt-half
    k_gemm1_i8<<<g1grid, 512, 0, stream>>>(qx, qwg, qwu, swg, swu, sxp, h16, sblk, &max_slots[1], 0);
    k_gemm1_i8<<<g1grid, 512, 0, stream>>>(qx, qwg, qwu, swg, swu, sxp, h16, sblk, &max_slots[1], 11);
    k_scale<<<1, 1, 0, stream>>>(clip_dn, &max_slots[1], shp);
    k_quant_h16_i8<<<4096, 256, 0, stream>>>(h16, sblk, shp, (int4*)qh, nh / 16);

    k_gemm2_i8<<<(M / 256) * (Hd / 256), 512, 0, stream>>>(qh, qwd, swd, shp, out);
}